// Round 16
// baseline (202.772 us; speedup 1.0000x reference)
//
#include <hip/hip_runtime.h>
#include <hip/hip_bf16.h>

#define DIM 64

typedef __attribute__((ext_vector_type(4)))  float f32x4;
typedef __attribute__((ext_vector_type(2)))  float f32x2;
typedef __attribute__((ext_vector_type(8)))  short short8;
typedef __attribute__((ext_vector_type(4)))  unsigned short u16x4;
typedef __attribute__((ext_vector_type(2)))  unsigned int u32x2;

// ---------- wave helpers (wave64) ----------
static __device__ __forceinline__ float wave_sum64(float v) {
    v += __shfl_xor(v, 1, 64);
    v += __shfl_xor(v, 2, 64);
    v += __shfl_xor(v, 4, 64);
    v += __shfl_xor(v, 8, 64);
    v += __shfl_xor(v, 16, 64);
    v += __shfl_xor(v, 32, 64);
    return v;
}

static __device__ __forceinline__ float b2f(unsigned short u) {
    return __uint_as_float(((unsigned int)u) << 16);
}
static __device__ __forceinline__ unsigned short f2b(float f) {
    unsigned int u = __float_as_uint(f);
    unsigned int rounded = u + 0x7fff + ((u >> 16) & 1);
    return (unsigned short)(rounded >> 16);
}
static __device__ __forceinline__ float b2f_lo(unsigned int u) {
    return __uint_as_float(u << 16);
}
static __device__ __forceinline__ float b2f_hi(unsigned int u) {
    return __uint_as_float(u & 0xffff0000u);
}

#define PCHUNK 8192
#define BCAP 4096

// ---------- fused wconv + zero-row + per-chunk LDS bucket histogram ----------
// Replaces the 800K random global atomicAdd histogram (round-15: 40us of
// memory-side atomic serialization) with LDS-aggregated bucket counts:
// ~100K atomics into a 4KB bcnt array.
__global__ __launch_bounds__(256) void k_wbhist(
        const float* __restrict__ We, const float* __restrict__ Wb,
        const float* __restrict__ Ws, unsigned short* __restrict__ wcvt,
        int L, int blocksW, unsigned short* __restrict__ hb_zero_row,
        const int* __restrict__ dst, int* __restrict__ bcnt, int E) {
    __shared__ int hist[1024];
    int bid = blockIdx.x;
    if (bid < blocksW) {
        int i = bid * 256 + threadIdx.x;
        int total = L * 3 * 4096;
        if (i >= total) return;
        int pos  = i & 4095;
        int lm   = i >> 12;
        int mode = lm % 3;
        int l    = lm / 3;
        const float* W = (mode == 0) ? We : (mode == 1) ? Wb : Ws;
        float v = W[(size_t)l * 4096 + pos];
        unsigned short hi = f2b(v);
        unsigned short lo = f2b(v - b2f(hi));
        wcvt[((size_t)lm * 2 + 0) * 4096 + pos] = hi;
        wcvt[((size_t)lm * 2 + 1) * 4096 + pos] = lo;
        return;
    }
    if (bid == blocksW) {
        if (threadIdx.x < 192) hb_zero_row[threadIdx.x] = 0;
        return;
    }
    // bucket histogram for chunk
    int chunk = bid - blocksW - 1;
    int base = chunk * PCHUNK;
    int cnt = E - base; if (cnt > PCHUNK) cnt = PCHUNK;
    int t = threadIdx.x;
    for (int i = t; i < 1024; i += 256) hist[i] = 0;
    __syncthreads();
    for (int k = t; k < cnt; k += 256) {
        int b = dst[base + k] >> 6;
        atomicAdd(&hist[b], 1);
    }
    __syncthreads();
    for (int b = t; b < 1024; b += 256) {
        int h = hist[b];
        if (h > 0) atomicAdd(&bcnt[b], h);
    }
}

// single block: scan bucket counts -> bbase (exclusive), init bcur, row_start[n]=E
__global__ __launch_bounds__(1024) void k_bscan(const int* __restrict__ bcnt,
                                                int* __restrict__ bbase,
                                                int* __restrict__ bcur,
                                                int* __restrict__ row_start,
                                                int n, int E) {
    __shared__ int buf[1024];
    int t = threadIdx.x;
    int v = bcnt[t];
    buf[t] = v;
    __syncthreads();
    for (int off = 1; off < 1024; off <<= 1) {
        int x = (t >= off) ? buf[t - off] : 0;
        __syncthreads();
        buf[t] += x;
        __syncthreads();
    }
    int excl = buf[t] - v;
    bbase[t] = excl;
    bcur[t]  = excl;
    if (t == 1023) {
        bbase[1024] = buf[1023];
        row_start[n] = E;
    }
}

// Pass 1: partition edges into bucket-contiguous ebuf[], packed (dst<<16)|src.
__global__ __launch_bounds__(256) void k_part(const int* __restrict__ src,
                                              const int* __restrict__ dst,
                                              int* __restrict__ bcur,
                                              unsigned int* __restrict__ ebuf,
                                              int E) {
    __shared__ int hist[1024];
    __shared__ int aux[256];
    __shared__ int delta[1024];
    __shared__ unsigned int stage[PCHUNK];

    int t = threadIdx.x;
    int base = blockIdx.x * PCHUNK;
    int cnt = E - base; if (cnt > PCHUNK) cnt = PCHUNK;

#pragma unroll
    for (int i = t; i < 1024; i += 256) hist[i] = 0;
    __syncthreads();

    for (int k = t; k < cnt; k += 256) {
        int b = dst[base + k] >> 6;
        atomicAdd(&hist[b], 1);
    }
    __syncthreads();

    int i4 = 4 * t;
    int a0 = hist[i4], a1 = hist[i4 + 1], a2 = hist[i4 + 2], a3 = hist[i4 + 3];
    int s = a0 + a1 + a2 + a3;
    aux[t] = s;
    __syncthreads();
    for (int off = 1; off < 256; off <<= 1) {
        int x = (t >= off) ? aux[t - off] : 0;
        __syncthreads();
        aux[t] += x;
        __syncthreads();
    }
    int excl = aux[t] - s;
    hist[i4]     = excl;
    hist[i4 + 1] = excl + a0;
    hist[i4 + 2] = excl + a0 + a1;
    hist[i4 + 3] = excl + a0 + a1 + a2;
    __syncthreads();

    int total = aux[255];
    for (int b = t; b < 1024; b += 256) {
        int st = hist[b];
        int nx = (b + 1 < 1024) ? hist[b + 1] : total;
        int cb = nx - st;
        if (cb > 0) {
            int gb = atomicAdd(&bcur[b], cb);
            delta[b] = gb - st;
        }
    }
    __syncthreads();

    for (int k = t; k < cnt; k += 256) {
        unsigned int d = (unsigned int)dst[base + k];
        unsigned int sv = (unsigned int)src[base + k];
        int b = (int)(d >> 6);
        int pos = atomicAdd(&hist[b], 1);
        stage[pos] = (d << 16) | sv;
    }
    __syncthreads();

    for (int p = t; p < cnt; p += 256) {
        unsigned int v = stage[p];
        int b = (int)(v >> 22);
        ebuf[delta[b] + p] = v;
    }
}

// Pass 2: per-bucket: per-node counts in LDS -> row_start (coalesced) + CSR slice.
__global__ __launch_bounds__(256) void k_bfill2(const unsigned int* __restrict__ ebuf,
                                                const int* __restrict__ bbase,
                                                int* __restrict__ row_start,
                                                int* __restrict__ csr_src,
                                                int n) {
    __shared__ int cnt64[64];
    __shared__ int lcur[64];
    __shared__ unsigned int evals[BCAP];
    __shared__ int lcsr[BCAP];
    int b = blockIdx.x;
    int t = threadIdx.x;
    int nodeLo = b * 64;
    int gLo = bbase[b];
    int gHi = bbase[b + 1];
    int cntB = gHi - gLo;

    if (t < 64) cnt64[t] = 0;
    __syncthreads();

    if (cntB <= BCAP) {
        for (int p = t; p < cntB; p += 256) {
            unsigned int v = ebuf[gLo + p];
            evals[p] = v;
            atomicAdd(&cnt64[(int)(v >> 16) - nodeLo], 1);
        }
        __syncthreads();
        int v0 = (t < 64) ? cnt64[t] : 0;
        // inclusive scan of cnt64
        for (int off = 1; off < 64; off <<= 1) {
            int x = (t < 64 && t >= off) ? cnt64[t - off] : 0;
            __syncthreads();
            if (t < 64) cnt64[t] += x;
            __syncthreads();
        }
        if (t < 64) {
            int pref = cnt64[t] - v0;      // exclusive
            lcur[t] = pref;
            int node = nodeLo + t;
            if (node < n) row_start[node] = gLo + pref;
        }
        __syncthreads();
        for (int p = t; p < cntB; p += 256) {
            unsigned int v = evals[p];
            int li = (int)(v >> 16) - nodeLo;
            int slot = atomicAdd(&lcur[li], 1);
            lcsr[slot] = (int)(v & 0xFFFFu);
        }
        __syncthreads();
        for (int p = t; p < cntB; p += 256) csr_src[gLo + p] = lcsr[p];
    } else {
        // fallback (not expected at this E/N)
        for (int p = t; p < cntB; p += 256) {
            unsigned int v = ebuf[gLo + p];
            atomicAdd(&cnt64[(int)(v >> 16) - nodeLo], 1);
        }
        __syncthreads();
        int v0 = (t < 64) ? cnt64[t] : 0;
        for (int off = 1; off < 64; off <<= 1) {
            int x = (t < 64 && t >= off) ? cnt64[t - off] : 0;
            __syncthreads();
            if (t < 64) cnt64[t] += x;
            __syncthreads();
        }
        if (t < 64) {
            int pref = cnt64[t] - v0;
            lcur[t] = pref;
            int node = nodeLo + t;
            if (node < n) row_start[node] = gLo + pref;
        }
        __syncthreads();
        for (int p = t; p < cntB; p += 256) {
            unsigned int v = ebuf[gLo + p];
            int li = (int)(v >> 16) - nodeLo;
            int slot = atomicAdd(&lcur[li], 1);
            csr_src[gLo + slot] = (int)(v & 0xFFFFu);
        }
    }
}

// ---------- fallback CSR path (N > 65536 only) ----------
__global__ void k_hist(const int* __restrict__ dst, int* __restrict__ cnt, int E) {
    int e = blockIdx.x * blockDim.x + threadIdx.x;
    if (e < E) atomicAdd(&cnt[dst[e]], 1);
}
__global__ __launch_bounds__(1024) void k_scan1(const int* __restrict__ cnt,
                                                int* __restrict__ partial,
                                                int* __restrict__ blocksum, int n) {
    __shared__ int buf[1024];
    int t = threadIdx.x;
    int i = blockIdx.x * 1024 + t;
    int v = (i < n) ? cnt[i] : 0;
    buf[t] = v;
    __syncthreads();
    for (int off = 1; off < 1024; off <<= 1) {
        int x = (t >= off) ? buf[t - off] : 0;
        __syncthreads();
        buf[t] += x;
        __syncthreads();
    }
    if (i < n) partial[i] = buf[t];
    if (t == 1023) blocksum[blockIdx.x] = buf[1023];
}
__global__ __launch_bounds__(1024) void k_scan2(int* __restrict__ blocksum, int nb) {
    __shared__ int buf[1024];
    int t = threadIdx.x;
    buf[t] = (t < nb) ? blocksum[t] : 0;
    __syncthreads();
    for (int off = 1; off < 1024; off <<= 1) {
        int x = (t >= off) ? buf[t - off] : 0;
        __syncthreads();
        buf[t] += x;
        __syncthreads();
    }
    if (t < nb) blocksum[t] = buf[t];
}
__global__ void k_scan3(const int* __restrict__ partial, const int* __restrict__ blocksum,
                        const int* __restrict__ cnt,
                        int* __restrict__ row_start, int* __restrict__ cursor, int n) {
    int i = blockIdx.x * blockDim.x + threadIdx.x;
    if (i == 0) row_start[0] = 0;
    if (i < n) {
        int b = i >> 10;
        int add = (b > 0) ? blocksum[b - 1] : 0;
        int incl = partial[i] + add;
        row_start[i + 1] = incl;
        cursor[i] = incl - cnt[i];
    }
}
__global__ void k_fill(const int* __restrict__ src, const int* __restrict__ dst,
                       int* __restrict__ cursor, int* __restrict__ csr_src, int E) {
    int e = blockIdx.x * blockDim.x + threadIdx.x;
    if (e < E) {
        int p = atomicAdd(&cursor[dst[e]], 1);
        csr_src[p] = src[e];
    }
}
__global__ __launch_bounds__(256) void k_wconv_fb(
        const float* __restrict__ We, const float* __restrict__ Wb,
        const float* __restrict__ Ws, unsigned short* __restrict__ wcvt,
        int L, int blocksW, unsigned short* __restrict__ hb_zero_row) {
    if ((int)blockIdx.x >= blocksW) {
        if (threadIdx.x < 192) hb_zero_row[threadIdx.x] = 0;
        return;
    }
    int i = blockIdx.x * 256 + threadIdx.x;
    int total = L * 3 * 4096;
    if (i >= total) return;
    int pos  = i & 4095;
    int lm   = i >> 12;
    int mode = lm % 3;
    int l    = lm / 3;
    const float* W = (mode == 0) ? We : (mode == 1) ? Wb : Ws;
    float v = W[(size_t)l * 4096 + pos];
    unsigned short hi = f2b(v);
    unsigned short lo = f2b(v - b2f(hi));
    wcvt[((size_t)lm * 2 + 0) * 4096 + pos] = hi;
    wcvt[((size_t)lm * 2 + 1) * 4096 + pos] = lo;
}

// ---------- Phase A via MFMA ----------
// hb column order within a mode is PERMUTED: packed col c = 4*mrow + t holds
// feature f = 16*t + mrow. Aggregation commutes; phaseB un-permutes.
__global__ __launch_bounds__(256) void k_phaseA_mfma(
        const float* __restrict__ Xe, const float* __restrict__ Xb, const float* __restrict__ Xs,
        const unsigned short* __restrict__ wcvt,
        const float* __restrict__ be, const float* __restrict__ bb, const float* __restrict__ bs,
        unsigned short* __restrict__ hb, const float* __restrict__ curv,
        int n, int ntiles, int wavesPerMode) {
    int gtid = blockIdx.x * blockDim.x + threadIdx.x;
    int gw   = gtid >> 6;
    int lane = gtid & 63;
    int mode = gw / wavesPerMode;
    if (mode >= 3) return;
    int w0   = gw - mode * wavesPerMode;

    int mrow  = lane & 15;
    int half  = lane >> 4;

    const float* X    = (mode == 0) ? Xe : (mode == 1) ? Xb : Xs;
    const float* bias = (mode == 0) ? be : (mode == 1) ? bb : bs;
    float sc = sqrtf(curv[0]);

    const unsigned short* whi = wcvt + ((size_t)mode * 2 + 0) * 4096;
    const unsigned short* wlo = wcvt + ((size_t)mode * 2 + 1) * 4096;
    short8 b_hi[4][2], b_lo[4][2];
#pragma unroll
    for (int t = 0; t < 4; ++t) {
        int wrow = 16 * t + mrow;
#pragma unroll
        for (int kc = 0; kc < 2; ++kc) {
            int off = wrow * DIM + 32 * kc + 8 * half;
            b_hi[t][kc] = *reinterpret_cast<const short8*>(whi + off);
            b_lo[t][kc] = *reinterpret_cast<const short8*>(wlo + off);
        }
    }
    float bl[4];
#pragma unroll
    for (int t = 0; t < 4; ++t) bl[t] = bias[16 * t + mrow];

    for (int tile = w0; tile < ntiles; tile += wavesPerMode) {
        int node0 = tile * 16;
        int row = node0 + mrow;
        int rowc = (row < n) ? row : (n - 1);
        const float* xp = X + (size_t)rowc * DIM + 8 * half;
        float xv[16];
        {
            const float4* p0 = reinterpret_cast<const float4*>(xp);
            const float4* p1 = reinterpret_cast<const float4*>(xp + 32);
            float4 a = p0[0], b = p0[1], c = p1[0], d = p1[1];
            xv[0]=a.x; xv[1]=a.y; xv[2]=a.z; xv[3]=a.w;
            xv[4]=b.x; xv[5]=b.y; xv[6]=b.z; xv[7]=b.w;
            xv[8]=c.x; xv[9]=c.y; xv[10]=c.z; xv[11]=c.w;
            xv[12]=d.x; xv[13]=d.y; xv[14]=d.z; xv[15]=d.w;
        }

        float scale = 1.0f;
        if (mode != 0) {
            float ss = 0.f;
#pragma unroll
            for (int i = 0; i < 16; ++i) ss = fmaf(xv[i], xv[i], ss);
            ss += __shfl_xor(ss, 16, 64);
            ss += __shfl_xor(ss, 32, 64);
            if (mode == 1) {
                float dn = fmaxf(sqrtf(ss), 1e-10f);
                scale = (2.0f / sc) * atanhf(sc * dn) / dn;
            } else {
                float dn = fmaxf(sqrtf(ss), 1e-12f);
                scale = 1.0f / dn;
            }
        }

        short8 a_hi0, a_hi1, a_lo0, a_lo1;
#pragma unroll
        for (int i = 0; i < 8; ++i) {
            float s0 = xv[i] * scale;
            unsigned short h0 = f2b(s0);
            a_hi0[i] = (short)h0;
            a_lo0[i] = (short)f2b(s0 - b2f(h0));
            float s1 = xv[8 + i] * scale;
            unsigned short h1 = f2b(s1);
            a_hi1[i] = (short)h1;
            a_lo1[i] = (short)f2b(s1 - b2f(h1));
        }

        f32x4 acc[4];
#pragma unroll
        for (int t = 0; t < 4; ++t) {
            f32x4 a = {0.f, 0.f, 0.f, 0.f};
            a = __builtin_amdgcn_mfma_f32_16x16x32_bf16(a_hi0, b_hi[t][0], a, 0, 0, 0);
            a = __builtin_amdgcn_mfma_f32_16x16x32_bf16(a_hi1, b_hi[t][1], a, 0, 0, 0);
            a = __builtin_amdgcn_mfma_f32_16x16x32_bf16(a_lo0, b_hi[t][0], a, 0, 0, 0);
            a = __builtin_amdgcn_mfma_f32_16x16x32_bf16(a_lo1, b_hi[t][1], a, 0, 0, 0);
            a = __builtin_amdgcn_mfma_f32_16x16x32_bf16(a_hi0, b_lo[t][0], a, 0, 0, 0);
            a = __builtin_amdgcn_mfma_f32_16x16x32_bf16(a_hi1, b_lo[t][1], a, 0, 0, 0);
            acc[t] = a;
        }

        float v[4][4];
#pragma unroll
        for (int t = 0; t < 4; ++t) {
#pragma unroll
            for (int r = 0; r < 4; ++r) v[t][r] = acc[t][r] + bl[t];
        }

        if (mode == 2) {
#pragma unroll
            for (int r = 0; r < 4; ++r) {
                float s = v[0][r]*v[0][r] + v[1][r]*v[1][r] + v[2][r]*v[2][r] + v[3][r]*v[3][r];
                s += __shfl_xor(s, 1, 64);
                s += __shfl_xor(s, 2, 64);
                s += __shfl_xor(s, 4, 64);
                s += __shfl_xor(s, 8, 64);
                float inv = 1.0f / fmaxf(sqrtf(s), 1e-12f);
#pragma unroll
                for (int t = 0; t < 4; ++t) v[t][r] *= inv;
            }
        }

#pragma unroll
        for (int r = 0; r < 4; ++r) {
            int orow = node0 + half * 4 + r;
            if (orow < n) {
                u16x4 pk;
                pk.x = f2b(v[0][r]); pk.y = f2b(v[1][r]);
                pk.z = f2b(v[2][r]); pk.w = f2b(v[3][r]);
                *reinterpret_cast<u16x4*>(hb + (size_t)orow * 192 + mode * 64 + 4 * mrow) = pk;
            }
        }
    }
}

// ---------- Phase B: asm gathers + zero-row tails + packed f32 adds ----------
#define GL(i, gname, vt) \
    "v_readlane_b32 %[st], %[idx], " #i "\n\t" \
    "s_mul_i32 %[st], %[st], 384\n\t" \
    "v_add_u32 %[" vt "], %[st], %[lo]\n\t" \
    "global_load_dwordx2 %[" gname "], %[" vt "], %[bs]\n\t"

#define ACC2(gi) { \
    f32x2 v01, v23; \
    v01.x = b2f_lo(gi.x); v01.y = b2f_hi(gi.x); \
    v23.x = b2f_lo(gi.y); v23.y = b2f_hi(gi.y); \
    asm volatile("v_pk_add_f32 %0, %1, %0" : "+v"(a01) : "v"(v01)); \
    asm volatile("v_pk_add_f32 %0, %1, %0" : "+v"(a23) : "v"(v23)); }

__global__ __launch_bounds__(256) void k_phaseB(const unsigned short* __restrict__ hb,
                                                const int* __restrict__ row_start,
                                                const int* __restrict__ csr_src,
                                                float* __restrict__ e_out,
                                                float* __restrict__ b_out,
                                                float* __restrict__ s_out,
                                                const float* __restrict__ curv,
                                                int n) {
    __shared__ float smem[4][192];
    int gtid = blockIdx.x * blockDim.x + threadIdx.x;
    int wid  = gtid >> 6;
    int lane = threadIdx.x & 63;
    int w    = threadIdx.x >> 6;
    if (wid >= n) return;

    int beg = row_start[wid];
    int end = row_start[wid + 1];

    const void* hbp = (const void*)hb;
    unsigned int lane_off = (unsigned int)lane * 8u;
    bool active = lane < 48;

    f32x2 a01 = {0.f, 0.f};
    f32x2 a23 = {0.f, 0.f};

    if (active) {
        int li0 = beg + (lane & 15);
        int lic0 = (li0 < end) ? li0 : (end - 1);
        unsigned int tv0 = (end > beg) ? (unsigned int)csr_src[lic0] : (unsigned int)n;
        unsigned int idxv = (li0 < end) ? tv0 : (unsigned int)n;

        for (int j = beg; j < end; j += 16) {
            u32x2 g0, g1, g2, g3, g4, g5, g6, g7;
            u32x2 g8, g9, g10, g11, g12, g13, g14, g15;
            unsigned int st, vt0, vt1;
            asm volatile(
                GL(0,  "g0",  "vt0") GL(1,  "g1",  "vt1")
                GL(2,  "g2",  "vt0") GL(3,  "g3",  "vt1")
                GL(4,  "g4",  "vt0") GL(5,  "g5",  "vt1")
                GL(6,  "g6",  "vt0") GL(7,  "g7",  "vt1")
                GL(8,  "g8",  "vt0") GL(9,  "g9",  "vt1")
                GL(10, "g10", "vt0") GL(11, "g11", "vt1")
                GL(12, "g12", "vt0") GL(13, "g13", "vt1")
                GL(14, "g14", "vt0") GL(15, "g15", "vt1")
                : [g0]"=&v"(g0),  [g1]"=&v"(g1),  [g2]"=&v"(g2),  [g3]"=&v"(g3),
                  [g4]"=&v"(g4),  [g5]"=&v"(g5),  [g6]"=&v"(g6),  [g7]"=&v"(g7),
                  [g8]"=&v"(g8),  [g9]"=&v"(g9),  [g10]"=&v"(g10),[g11]"=&v"(g11),
                  [g12]"=&v"(g12),[g13]"=&v"(g13),[g14]"=&v"(g14),[g15]"=&v"(g15),
                  [st]"=&s"(st), [vt0]"=&v"(vt0), [vt1]"=&v"(vt1)
                : [idx]"v"(idxv), [lo]"v"(lane_off), [bs]"s"(hbp)
                : "memory");

            int jn = j + 16;
            unsigned int idx_next = idxv;
            if (jn < end) {
                int li = jn + (lane & 15);
                int lic = (li < end) ? li : (end - 1);
                unsigned int tv = (unsigned int)csr_src[lic];
                idx_next = (li < end) ? tv : (unsigned int)n;
            }

            asm volatile("s_waitcnt vmcnt(0)" ::: "memory");
            __builtin_amdgcn_sched_barrier(0);

            ACC2(g0)  ACC2(g1)  ACC2(g2)  ACC2(g3)
            ACC2(g4)  ACC2(g5)  ACC2(g6)  ACC2(g7)
            ACC2(g8)  ACC2(g9)  ACC2(g10) ACC2(g11)
            ACC2(g12) ACC2(g13) ACC2(g14) ACC2(g15)

            idxv = idx_next;
        }
        smem[w][4 * lane + 0] = a01.x;
        smem[w][4 * lane + 1] = a01.y;
        smem[w][4 * lane + 2] = a23.x;
        smem[w][4 * lane + 3] = a23.y;
    }
    asm volatile("s_waitcnt lgkmcnt(0)" ::: "memory");

    int c = 4 * (lane & 15) + (lane >> 4);
    float fe = smem[w][c];
    float fb = smem[w][64 + c];
    float fs = smem[w][128 + c];

    int cnt = end - beg;
    float inv = 1.0f / (float)(cnt > 0 ? cnt : 1);
    fe *= inv; fb *= inv; fs *= inv;

    e_out[(size_t)wid * DIM + lane] = (fe >= 0.f) ? fe : 0.2f * fe;

    float cc = curv[0];
    float sc = sqrtf(cc);
    float vn = fmaxf(sqrtf(wave_sum64(fb * fb)), 1e-10f);
    float scale = tanhf(sc * vn * 0.5f) / (sc * vn);
    b_out[(size_t)wid * DIM + lane] = fb * scale;

    float nr = fmaxf(sqrtf(wave_sum64(fs * fs)), 1e-12f);
    s_out[(size_t)wid * DIM + lane] = fs / nr;
}

extern "C" void kernel_launch(void* const* d_in, const int* in_sizes, int n_in,
                              void* d_out, int out_size, void* d_ws, size_t ws_size,
                              hipStream_t stream) {
    const float* e0   = (const float*)d_in[0];
    const float* b0   = (const float*)d_in[1];
    const float* s0   = (const float*)d_in[2];
    const float* We   = (const float*)d_in[3];
    const float* be   = (const float*)d_in[4];
    const float* Wb   = (const float*)d_in[5];
    const float* bb   = (const float*)d_in[6];
    const float* Ws   = (const float*)d_in[7];
    const float* bs   = (const float*)d_in[8];
    const float* bcurv= (const float*)d_in[9];
    const int*   src  = (const int*)d_in[11];
    const int*   dst  = (const int*)d_in[12];

    const int N = in_sizes[0] / DIM;
    const int E = in_sizes[11];
    const int L = in_sizes[3] / (DIM * DIM);

    // workspace carve
    const int Npad = (N + 1023) & ~1023;
    int* cnt       = (int*)d_ws;                  // Npad (fallback only)
    int* row_start = cnt + Npad;                  // Npad+64
    int* cursor    = row_start + Npad + 64;       // Npad (fallback/scan partial)
    int* blocksum  = cursor + Npad;               // 1024
    int* bcur      = blocksum + 1024;             // 1024
    int* bcnt      = bcur + 1024;                 // 1024
    int* bbase     = bcnt + 1024;                 // 1032
    int* csr_src   = bbase + 1032;                // E
    unsigned int* ebuf = (unsigned int*)(csr_src + ((E + 63) & ~63));       // E
    unsigned short* hb   = (unsigned short*)(ebuf + ((E + 63) & ~63));      // (N+1)*192 bf16
    unsigned short* wcvt = hb + (size_t)(N + 1) * 192;  // L*3*2*4096 bf16

    float* out_e = (float*)d_out;
    float* out_b = out_e + (size_t)N * DIM;
    float* out_s = out_b + (size_t)N * DIM;

    const int ntiles = (N + 15) / 16;
    const int wavesPerMode = 1024;
    const int grdA = (3 * wavesPerMode) / 4;
    const int grdE = (E + 255) / 256;
    const int grdB = (N * DIM + 255) / 256;
    const int wtot = L * 3 * 4096;
    const int grdW = (wtot + 255) / 256;
    const int NB2  = (N + 63) / 64;
    const int nchunk = (E + PCHUNK - 1) / PCHUNK;

    if (N <= 65536) {
        hipMemsetAsync(bcnt, 0, 1024 * sizeof(int), stream);
        // wconv + zero-row + bucket histogram (LDS-aggregated)
        k_wbhist<<<grdW + 1 + nchunk, 256, 0, stream>>>(
            We, Wb, Ws, wcvt, L, grdW, hb + (size_t)N * 192, dst, bcnt, E);
        k_bscan<<<1, 1024, 0, stream>>>(bcnt, bbase, bcur, row_start, N, E);
        k_part<<<nchunk, 256, 0, stream>>>(src, dst, bcur, ebuf, E);
        k_bfill2<<<NB2, 256, 0, stream>>>(ebuf, bbase, row_start, csr_src, N);
    } else {
        hipMemsetAsync(cnt, 0, (size_t)N * sizeof(int), stream);
        k_wconv_fb<<<grdW + 1, 256, 0, stream>>>(We, Wb, Ws, wcvt, L, grdW,
                                                 hb + (size_t)N * 192);
        k_hist<<<grdE, 256, 0, stream>>>(dst, cnt, E);
        int nb = (N + 1023) / 1024;
        k_scan1<<<nb, 1024, 0, stream>>>(cnt, cursor, blocksum, N);
        k_scan2<<<1, 1024, 0, stream>>>(blocksum, nb);
        k_scan3<<<(N + 255) / 256, 256, 0, stream>>>(cursor, blocksum, cnt,
                                                     row_start, cursor, N);
        k_fill<<<grdE, 256, 0, stream>>>(src, dst, cursor, csr_src, E);
    }

    for (int l = 0; l < L; ++l) {
        const float* Xe = (l == 0) ? e0 : out_e;
        const float* Xb = (l == 0) ? b0 : out_b;
        const float* Xs = (l == 0) ? s0 : out_s;

        k_phaseA_mfma<<<grdA, 256, 0, stream>>>(
            Xe, Xb, Xs,
            wcvt + (size_t)l * 3 * 2 * 4096,
            be + (size_t)l * DIM, bb + (size_t)l * DIM, bs + (size_t)l * DIM,
            hb, bcurv, N, ntiles, wavesPerMode);

        k_phaseB<<<grdB, 256, 0, stream>>>(hb, row_start, csr_src,
                                           out_e, out_b, out_s, bcurv, N);
    }
}

// Round 17
// 170.845 us; speedup vs baseline: 1.1869x; 1.1869x over previous
//
#include <hip/hip_runtime.h>
#include <hip/hip_bf16.h>

#define DIM 64

typedef __attribute__((ext_vector_type(4)))  float f32x4;
typedef __attribute__((ext_vector_type(2)))  float f32x2;
typedef __attribute__((ext_vector_type(8)))  short short8;
typedef __attribute__((ext_vector_type(4)))  unsigned short u16x4;
typedef __attribute__((ext_vector_type(2)))  unsigned int u32x2;

// ---------- wave helpers (wave64) ----------
static __device__ __forceinline__ float wave_sum64(float v) {
    v += __shfl_xor(v, 1, 64);
    v += __shfl_xor(v, 2, 64);
    v += __shfl_xor(v, 4, 64);
    v += __shfl_xor(v, 8, 64);
    v += __shfl_xor(v, 16, 64);
    v += __shfl_xor(v, 32, 64);
    return v;
}

static __device__ __forceinline__ float b2f(unsigned short u) {
    return __uint_as_float(((unsigned int)u) << 16);
}
static __device__ __forceinline__ unsigned short f2b(float f) {
    unsigned int u = __float_as_uint(f);
    unsigned int rounded = u + 0x7fff + ((u >> 16) & 1);
    return (unsigned short)(rounded >> 16);
}
static __device__ __forceinline__ float b2f_lo(unsigned int u) {
    return __uint_as_float(u << 16);
}
static __device__ __forceinline__ float b2f_hi(unsigned int u) {
    return __uint_as_float(u & 0xffff0000u);
}

#define PCHUNK 8192
#define BCAP 4096

// ---------- fused wconv + zero-row + per-chunk LDS bucket histogram ----------
__global__ __launch_bounds__(256) void k_wbhist(
        const float* __restrict__ We, const float* __restrict__ Wb,
        const float* __restrict__ Ws, unsigned short* __restrict__ wcvt,
        int L, int blocksW, unsigned short* __restrict__ hb_zero_row,
        const int* __restrict__ dst, int* __restrict__ bcnt, int E) {
    __shared__ int hist[1024];
    int bid = blockIdx.x;
    if (bid < blocksW) {
        int i = bid * 256 + threadIdx.x;
        int total = L * 3 * 4096;
        if (i >= total) return;
        int pos  = i & 4095;
        int lm   = i >> 12;
        int mode = lm % 3;
        int l    = lm / 3;
        const float* W = (mode == 0) ? We : (mode == 1) ? Wb : Ws;
        float v = W[(size_t)l * 4096 + pos];
        unsigned short hi = f2b(v);
        unsigned short lo = f2b(v - b2f(hi));
        wcvt[((size_t)lm * 2 + 0) * 4096 + pos] = hi;
        wcvt[((size_t)lm * 2 + 1) * 4096 + pos] = lo;
        return;
    }
    if (bid == blocksW) {
        if (threadIdx.x < 192) hb_zero_row[threadIdx.x] = 0;
        return;
    }
    int chunk = bid - blocksW - 1;
    int base = chunk * PCHUNK;
    int cnt = E - base; if (cnt > PCHUNK) cnt = PCHUNK;
    int t = threadIdx.x;
    for (int i = t; i < 1024; i += 256) hist[i] = 0;
    __syncthreads();
    for (int k = t; k < cnt; k += 256) {
        int b = dst[base + k] >> 6;
        atomicAdd(&hist[b], 1);
    }
    __syncthreads();
    for (int b = t; b < 1024; b += 256) {
        int h = hist[b];
        if (h > 0) atomicAdd(&bcnt[b], h);
    }
}

// single block: scan bucket counts -> bbase (exclusive), init bcur, row_start[n]=E
__global__ __launch_bounds__(1024) void k_bscan(const int* __restrict__ bcnt,
                                                int* __restrict__ bbase,
                                                int* __restrict__ bcur,
                                                int* __restrict__ row_start,
                                                int n, int E) {
    __shared__ int buf[1024];
    int t = threadIdx.x;
    int v = bcnt[t];
    buf[t] = v;
    __syncthreads();
    for (int off = 1; off < 1024; off <<= 1) {
        int x = (t >= off) ? buf[t - off] : 0;
        __syncthreads();
        buf[t] += x;
        __syncthreads();
    }
    int excl = buf[t] - v;
    bbase[t] = excl;
    bcur[t]  = excl;
    if (t == 1023) {
        bbase[1024] = buf[1023];
        row_start[n] = E;
    }
}

// ---------- Phase A body ----------
// hb column order within a mode is PERMUTED: packed col c = 4*mrow + t holds
// feature f = 16*t + mrow. Aggregation commutes; phaseB un-permutes.
static __device__ __forceinline__ void phaseA_body(
        int gw, int lane,
        const float* __restrict__ Xe, const float* __restrict__ Xb, const float* __restrict__ Xs,
        const unsigned short* __restrict__ wcvt,
        const float* __restrict__ be, const float* __restrict__ bb, const float* __restrict__ bs,
        unsigned short* __restrict__ hb, const float* __restrict__ curv,
        int n, int ntiles, int wavesPerMode) {
    int mode = gw / wavesPerMode;
    if (mode >= 3) return;
    int w0   = gw - mode * wavesPerMode;

    int mrow  = lane & 15;
    int half  = lane >> 4;

    const float* X    = (mode == 0) ? Xe : (mode == 1) ? Xb : Xs;
    const float* bias = (mode == 0) ? be : (mode == 1) ? bb : bs;
    float sc = sqrtf(curv[0]);

    const unsigned short* whi = wcvt + ((size_t)mode * 2 + 0) * 4096;
    const unsigned short* wlo = wcvt + ((size_t)mode * 2 + 1) * 4096;
    short8 b_hi[4][2], b_lo[4][2];
#pragma unroll
    for (int t = 0; t < 4; ++t) {
        int wrow = 16 * t + mrow;
#pragma unroll
        for (int kc = 0; kc < 2; ++kc) {
            int off = wrow * DIM + 32 * kc + 8 * half;
            b_hi[t][kc] = *reinterpret_cast<const short8*>(whi + off);
            b_lo[t][kc] = *reinterpret_cast<const short8*>(wlo + off);
        }
    }
    float bl[4];
#pragma unroll
    for (int t = 0; t < 4; ++t) bl[t] = bias[16 * t + mrow];

    for (int tile = w0; tile < ntiles; tile += wavesPerMode) {
        int node0 = tile * 16;
        int row = node0 + mrow;
        int rowc = (row < n) ? row : (n - 1);
        const float* xp = X + (size_t)rowc * DIM + 8 * half;
        float xv[16];
        {
            const float4* p0 = reinterpret_cast<const float4*>(xp);
            const float4* p1 = reinterpret_cast<const float4*>(xp + 32);
            float4 a = p0[0], b = p0[1], c = p1[0], d = p1[1];
            xv[0]=a.x; xv[1]=a.y; xv[2]=a.z; xv[3]=a.w;
            xv[4]=b.x; xv[5]=b.y; xv[6]=b.z; xv[7]=b.w;
            xv[8]=c.x; xv[9]=c.y; xv[10]=c.z; xv[11]=c.w;
            xv[12]=d.x; xv[13]=d.y; xv[14]=d.z; xv[15]=d.w;
        }

        float scale = 1.0f;
        if (mode != 0) {
            float ss = 0.f;
#pragma unroll
            for (int i = 0; i < 16; ++i) ss = fmaf(xv[i], xv[i], ss);
            ss += __shfl_xor(ss, 16, 64);
            ss += __shfl_xor(ss, 32, 64);
            if (mode == 1) {
                float dn = fmaxf(sqrtf(ss), 1e-10f);
                scale = (2.0f / sc) * atanhf(sc * dn) / dn;
            } else {
                float dn = fmaxf(sqrtf(ss), 1e-12f);
                scale = 1.0f / dn;
            }
        }

        short8 a_hi0, a_hi1, a_lo0, a_lo1;
#pragma unroll
        for (int i = 0; i < 8; ++i) {
            float s0 = xv[i] * scale;
            unsigned short h0 = f2b(s0);
            a_hi0[i] = (short)h0;
            a_lo0[i] = (short)f2b(s0 - b2f(h0));
            float s1 = xv[8 + i] * scale;
            unsigned short h1 = f2b(s1);
            a_hi1[i] = (short)h1;
            a_lo1[i] = (short)f2b(s1 - b2f(h1));
        }

        f32x4 acc[4];
#pragma unroll
        for (int t = 0; t < 4; ++t) {
            f32x4 a = {0.f, 0.f, 0.f, 0.f};
            a = __builtin_amdgcn_mfma_f32_16x16x32_bf16(a_hi0, b_hi[t][0], a, 0, 0, 0);
            a = __builtin_amdgcn_mfma_f32_16x16x32_bf16(a_hi1, b_hi[t][1], a, 0, 0, 0);
            a = __builtin_amdgcn_mfma_f32_16x16x32_bf16(a_lo0, b_hi[t][0], a, 0, 0, 0);
            a = __builtin_amdgcn_mfma_f32_16x16x32_bf16(a_lo1, b_hi[t][1], a, 0, 0, 0);
            a = __builtin_amdgcn_mfma_f32_16x16x32_bf16(a_hi0, b_lo[t][0], a, 0, 0, 0);
            a = __builtin_amdgcn_mfma_f32_16x16x32_bf16(a_hi1, b_lo[t][1], a, 0, 0, 0);
            acc[t] = a;
        }

        float v[4][4];
#pragma unroll
        for (int t = 0; t < 4; ++t) {
#pragma unroll
            for (int r = 0; r < 4; ++r) v[t][r] = acc[t][r] + bl[t];
        }

        if (mode == 2) {
#pragma unroll
            for (int r = 0; r < 4; ++r) {
                float s = v[0][r]*v[0][r] + v[1][r]*v[1][r] + v[2][r]*v[2][r] + v[3][r]*v[3][r];
                s += __shfl_xor(s, 1, 64);
                s += __shfl_xor(s, 2, 64);
                s += __shfl_xor(s, 4, 64);
                s += __shfl_xor(s, 8, 64);
                float inv = 1.0f / fmaxf(sqrtf(s), 1e-12f);
#pragma unroll
                for (int t = 0; t < 4; ++t) v[t][r] *= inv;
            }
        }

#pragma unroll
        for (int r = 0; r < 4; ++r) {
            int orow = node0 + half * 4 + r;
            if (orow < n) {
                u16x4 pk;
                pk.x = f2b(v[0][r]); pk.y = f2b(v[1][r]);
                pk.z = f2b(v[2][r]); pk.w = f2b(v[3][r]);
                *reinterpret_cast<u16x4*>(hb + (size_t)orow * 192 + mode * 64 + 4 * mrow) = pk;
            }
        }
    }
}

// standalone phase A (layer 1 / fallback)
__global__ __launch_bounds__(256) void k_phaseA_mfma(
        const float* __restrict__ Xe, const float* __restrict__ Xb, const float* __restrict__ Xs,
        const unsigned short* __restrict__ wcvt,
        const float* __restrict__ be, const float* __restrict__ bb, const float* __restrict__ bs,
        unsigned short* __restrict__ hb, const float* __restrict__ curv,
        int n, int ntiles, int wavesPerMode) {
    int gtid = blockIdx.x * blockDim.x + threadIdx.x;
    phaseA_body(gtid >> 6, gtid & 63, Xe, Xb, Xs, wcvt, be, bb, bs, hb, curv,
                n, ntiles, wavesPerMode);
}

// ---------- fused: edge partition (pass 1) + phase A layer 0 ----------
// Both depend only on {wbhist, bscan}; complementary profiles (LDS-sort +
// coalesced IO vs MFMA compute). part's writes are merged (~13MB), so no
// write-path contention (round-12 lesson).
__global__ __launch_bounds__(256) void k_partA0(
        const int* __restrict__ src, const int* __restrict__ dst,
        int* __restrict__ bcur, unsigned int* __restrict__ ebuf, int E, int blocksP,
        const float* __restrict__ Xe, const float* __restrict__ Xb, const float* __restrict__ Xs,
        const unsigned short* __restrict__ wcvt,
        const float* __restrict__ be, const float* __restrict__ bb, const float* __restrict__ bs,
        unsigned short* __restrict__ hb, const float* __restrict__ curv,
        int n, int ntiles, int wavesPerMode) {
    if ((int)blockIdx.x >= blocksP) {
        int gtid = (blockIdx.x - blocksP) * 256 + threadIdx.x;
        phaseA_body(gtid >> 6, gtid & 63, Xe, Xb, Xs, wcvt, be, bb, bs, hb, curv,
                    n, ntiles, wavesPerMode);
        return;
    }
    __shared__ int hist[1024];
    __shared__ int aux[256];
    __shared__ int delta[1024];
    __shared__ unsigned int stage[PCHUNK];

    int t = threadIdx.x;
    int base = blockIdx.x * PCHUNK;
    int cnt = E - base; if (cnt > PCHUNK) cnt = PCHUNK;

#pragma unroll
    for (int i = t; i < 1024; i += 256) hist[i] = 0;
    __syncthreads();

    for (int k = t; k < cnt; k += 256) {
        int b = dst[base + k] >> 6;
        atomicAdd(&hist[b], 1);
    }
    __syncthreads();

    int i4 = 4 * t;
    int a0 = hist[i4], a1 = hist[i4 + 1], a2 = hist[i4 + 2], a3 = hist[i4 + 3];
    int s = a0 + a1 + a2 + a3;
    aux[t] = s;
    __syncthreads();
    for (int off = 1; off < 256; off <<= 1) {
        int x = (t >= off) ? aux[t - off] : 0;
        __syncthreads();
        aux[t] += x;
        __syncthreads();
    }
    int excl = aux[t] - s;
    hist[i4]     = excl;
    hist[i4 + 1] = excl + a0;
    hist[i4 + 2] = excl + a0 + a1;
    hist[i4 + 3] = excl + a0 + a1 + a2;
    __syncthreads();

    int total = aux[255];
    for (int b = t; b < 1024; b += 256) {
        int st = hist[b];
        int nx = (b + 1 < 1024) ? hist[b + 1] : total;
        int cb = nx - st;
        if (cb > 0) {
            int gb = atomicAdd(&bcur[b], cb);
            delta[b] = gb - st;
        }
    }
    __syncthreads();

    for (int k = t; k < cnt; k += 256) {
        unsigned int d = (unsigned int)dst[base + k];
        unsigned int sv = (unsigned int)src[base + k];
        int b = (int)(d >> 6);
        int pos = atomicAdd(&hist[b], 1);
        stage[pos] = (d << 16) | sv;
    }
    __syncthreads();

    for (int p = t; p < cnt; p += 256) {
        unsigned int v = stage[p];
        int b = (int)(v >> 22);
        ebuf[delta[b] + p] = v;
    }
}

// Pass 2: per-bucket: per-node counts in LDS -> row_start (coalesced) + CSR slice.
__global__ __launch_bounds__(256) void k_bfill2(const unsigned int* __restrict__ ebuf,
                                                const int* __restrict__ bbase,
                                                int* __restrict__ row_start,
                                                int* __restrict__ csr_src,
                                                int n) {
    __shared__ int cnt64[64];
    __shared__ int lcur[64];
    __shared__ unsigned int evals[BCAP];
    __shared__ int lcsr[BCAP];
    int b = blockIdx.x;
    int t = threadIdx.x;
    int nodeLo = b * 64;
    int gLo = bbase[b];
    int gHi = bbase[b + 1];
    int cntB = gHi - gLo;

    if (t < 64) cnt64[t] = 0;
    __syncthreads();

    if (cntB <= BCAP) {
        for (int p = t; p < cntB; p += 256) {
            unsigned int v = ebuf[gLo + p];
            evals[p] = v;
            atomicAdd(&cnt64[(int)(v >> 16) - nodeLo], 1);
        }
        __syncthreads();
        int v0 = (t < 64) ? cnt64[t] : 0;
        for (int off = 1; off < 64; off <<= 1) {
            int x = (t < 64 && t >= off) ? cnt64[t - off] : 0;
            __syncthreads();
            if (t < 64) cnt64[t] += x;
            __syncthreads();
        }
        if (t < 64) {
            int pref = cnt64[t] - v0;
            lcur[t] = pref;
            int node = nodeLo + t;
            if (node < n) row_start[node] = gLo + pref;
        }
        __syncthreads();
        for (int p = t; p < cntB; p += 256) {
            unsigned int v = evals[p];
            int li = (int)(v >> 16) - nodeLo;
            int slot = atomicAdd(&lcur[li], 1);
            lcsr[slot] = (int)(v & 0xFFFFu);
        }
        __syncthreads();
        for (int p = t; p < cntB; p += 256) csr_src[gLo + p] = lcsr[p];
    } else {
        for (int p = t; p < cntB; p += 256) {
            unsigned int v = ebuf[gLo + p];
            atomicAdd(&cnt64[(int)(v >> 16) - nodeLo], 1);
        }
        __syncthreads();
        int v0 = (t < 64) ? cnt64[t] : 0;
        for (int off = 1; off < 64; off <<= 1) {
            int x = (t < 64 && t >= off) ? cnt64[t - off] : 0;
            __syncthreads();
            if (t < 64) cnt64[t] += x;
            __syncthreads();
        }
        if (t < 64) {
            int pref = cnt64[t] - v0;
            lcur[t] = pref;
            int node = nodeLo + t;
            if (node < n) row_start[node] = gLo + pref;
        }
        __syncthreads();
        for (int p = t; p < cntB; p += 256) {
            unsigned int v = ebuf[gLo + p];
            int li = (int)(v >> 16) - nodeLo;
            int slot = atomicAdd(&lcur[li], 1);
            csr_src[gLo + slot] = (int)(v & 0xFFFFu);
        }
    }
}

// ---------- fallback CSR path (N > 65536 only) ----------
__global__ void k_hist(const int* __restrict__ dst, int* __restrict__ cnt, int E) {
    int e = blockIdx.x * blockDim.x + threadIdx.x;
    if (e < E) atomicAdd(&cnt[dst[e]], 1);
}
__global__ __launch_bounds__(1024) void k_scan1(const int* __restrict__ cnt,
                                                int* __restrict__ partial,
                                                int* __restrict__ blocksum, int n) {
    __shared__ int buf[1024];
    int t = threadIdx.x;
    int i = blockIdx.x * 1024 + t;
    int v = (i < n) ? cnt[i] : 0;
    buf[t] = v;
    __syncthreads();
    for (int off = 1; off < 1024; off <<= 1) {
        int x = (t >= off) ? buf[t - off] : 0;
        __syncthreads();
        buf[t] += x;
        __syncthreads();
    }
    if (i < n) partial[i] = buf[t];
    if (t == 1023) blocksum[blockIdx.x] = buf[1023];
}
__global__ __launch_bounds__(1024) void k_scan2(int* __restrict__ blocksum, int nb) {
    __shared__ int buf[1024];
    int t = threadIdx.x;
    buf[t] = (t < nb) ? blocksum[t] : 0;
    __syncthreads();
    for (int off = 1; off < 1024; off <<= 1) {
        int x = (t >= off) ? buf[t - off] : 0;
        __syncthreads();
        buf[t] += x;
        __syncthreads();
    }
    if (t < nb) blocksum[t] = buf[t];
}
__global__ void k_scan3(const int* __restrict__ partial, const int* __restrict__ blocksum,
                        const int* __restrict__ cnt,
                        int* __restrict__ row_start, int* __restrict__ cursor, int n) {
    int i = blockIdx.x * blockDim.x + threadIdx.x;
    if (i == 0) row_start[0] = 0;
    if (i < n) {
        int b = i >> 10;
        int add = (b > 0) ? blocksum[b - 1] : 0;
        int incl = partial[i] + add;
        row_start[i + 1] = incl;
        cursor[i] = incl - cnt[i];
    }
}
__global__ void k_fill(const int* __restrict__ src, const int* __restrict__ dst,
                       int* __restrict__ cursor, int* __restrict__ csr_src, int E) {
    int e = blockIdx.x * blockDim.x + threadIdx.x;
    if (e < E) {
        int p = atomicAdd(&cursor[dst[e]], 1);
        csr_src[p] = src[e];
    }
}
__global__ __launch_bounds__(256) void k_wconv_fb(
        const float* __restrict__ We, const float* __restrict__ Wb,
        const float* __restrict__ Ws, unsigned short* __restrict__ wcvt,
        int L, int blocksW, unsigned short* __restrict__ hb_zero_row) {
    if ((int)blockIdx.x >= blocksW) {
        if (threadIdx.x < 192) hb_zero_row[threadIdx.x] = 0;
        return;
    }
    int i = blockIdx.x * 256 + threadIdx.x;
    int total = L * 3 * 4096;
    if (i >= total) return;
    int pos  = i & 4095;
    int lm   = i >> 12;
    int mode = lm % 3;
    int l    = lm / 3;
    const float* W = (mode == 0) ? We : (mode == 1) ? Wb : Ws;
    float v = W[(size_t)l * 4096 + pos];
    unsigned short hi = f2b(v);
    unsigned short lo = f2b(v - b2f(hi));
    wcvt[((size_t)lm * 2 + 0) * 4096 + pos] = hi;
    wcvt[((size_t)lm * 2 + 1) * 4096 + pos] = lo;
}

// ---------- Phase B: asm gathers + zero-row tails + packed f32 adds ----------
#define GL(i, gname, vt) \
    "v_readlane_b32 %[st], %[idx], " #i "\n\t" \
    "s_mul_i32 %[st], %[st], 384\n\t" \
    "v_add_u32 %[" vt "], %[st], %[lo]\n\t" \
    "global_load_dwordx2 %[" gname "], %[" vt "], %[bs]\n\t"

#define ACC2(gi) { \
    f32x2 v01, v23; \
    v01.x = b2f_lo(gi.x); v01.y = b2f_hi(gi.x); \
    v23.x = b2f_lo(gi.y); v23.y = b2f_hi(gi.y); \
    asm volatile("v_pk_add_f32 %0, %1, %0" : "+v"(a01) : "v"(v01)); \
    asm volatile("v_pk_add_f32 %0, %1, %0" : "+v"(a23) : "v"(v23)); }

__global__ __launch_bounds__(256) void k_phaseB(const unsigned short* __restrict__ hb,
                                                const int* __restrict__ row_start,
                                                const int* __restrict__ csr_src,
                                                float* __restrict__ e_out,
                                                float* __restrict__ b_out,
                                                float* __restrict__ s_out,
                                                const float* __restrict__ curv,
                                                int n) {
    __shared__ float smem[4][192];
    int gtid = blockIdx.x * blockDim.x + threadIdx.x;
    int wid  = gtid >> 6;
    int lane = threadIdx.x & 63;
    int w    = threadIdx.x >> 6;
    if (wid >= n) return;

    int beg = row_start[wid];
    int end = row_start[wid + 1];

    const void* hbp = (const void*)hb;
    unsigned int lane_off = (unsigned int)lane * 8u;
    bool active = lane < 48;

    f32x2 a01 = {0.f, 0.f};
    f32x2 a23 = {0.f, 0.f};

    if (active) {
        int li0 = beg + (lane & 15);
        int lic0 = (li0 < end) ? li0 : (end - 1);
        unsigned int tv0 = (end > beg) ? (unsigned int)csr_src[lic0] : (unsigned int)n;
        unsigned int idxv = (li0 < end) ? tv0 : (unsigned int)n;

        for (int j = beg; j < end; j += 16) {
            u32x2 g0, g1, g2, g3, g4, g5, g6, g7;
            u32x2 g8, g9, g10, g11, g12, g13, g14, g15;
            unsigned int st, vt0, vt1;
            asm volatile(
                GL(0,  "g0",  "vt0") GL(1,  "g1",  "vt1")
                GL(2,  "g2",  "vt0") GL(3,  "g3",  "vt1")
                GL(4,  "g4",  "vt0") GL(5,  "g5",  "vt1")
                GL(6,  "g6",  "vt0") GL(7,  "g7",  "vt1")
                GL(8,  "g8",  "vt0") GL(9,  "g9",  "vt1")
                GL(10, "g10", "vt0") GL(11, "g11", "vt1")
                GL(12, "g12", "vt0") GL(13, "g13", "vt1")
                GL(14, "g14", "vt0") GL(15, "g15", "vt1")
                : [g0]"=&v"(g0),  [g1]"=&v"(g1),  [g2]"=&v"(g2),  [g3]"=&v"(g3),
                  [g4]"=&v"(g4),  [g5]"=&v"(g5),  [g6]"=&v"(g6),  [g7]"=&v"(g7),
                  [g8]"=&v"(g8),  [g9]"=&v"(g9),  [g10]"=&v"(g10),[g11]"=&v"(g11),
                  [g12]"=&v"(g12),[g13]"=&v"(g13),[g14]"=&v"(g14),[g15]"=&v"(g15),
                  [st]"=&s"(st), [vt0]"=&v"(vt0), [vt1]"=&v"(vt1)
                : [idx]"v"(idxv), [lo]"v"(lane_off), [bs]"s"(hbp)
                : "memory");

            int jn = j + 16;
            unsigned int idx_next = idxv;
            if (jn < end) {
                int li = jn + (lane & 15);
                int lic = (li < end) ? li : (end - 1);
                unsigned int tv = (unsigned int)csr_src[lic];
                idx_next = (li < end) ? tv : (unsigned int)n;
            }

            asm volatile("s_waitcnt vmcnt(0)" ::: "memory");
            __builtin_amdgcn_sched_barrier(0);

            ACC2(g0)  ACC2(g1)  ACC2(g2)  ACC2(g3)
            ACC2(g4)  ACC2(g5)  ACC2(g6)  ACC2(g7)
            ACC2(g8)  ACC2(g9)  ACC2(g10) ACC2(g11)
            ACC2(g12) ACC2(g13) ACC2(g14) ACC2(g15)

            idxv = idx_next;
        }
        smem[w][4 * lane + 0] = a01.x;
        smem[w][4 * lane + 1] = a01.y;
        smem[w][4 * lane + 2] = a23.x;
        smem[w][4 * lane + 3] = a23.y;
    }
    asm volatile("s_waitcnt lgkmcnt(0)" ::: "memory");

    int c = 4 * (lane & 15) + (lane >> 4);
    float fe = smem[w][c];
    float fb = smem[w][64 + c];
    float fs = smem[w][128 + c];

    int cnt = end - beg;
    float inv = 1.0f / (float)(cnt > 0 ? cnt : 1);
    fe *= inv; fb *= inv; fs *= inv;

    e_out[(size_t)wid * DIM + lane] = (fe >= 0.f) ? fe : 0.2f * fe;

    float cc = curv[0];
    float sc = sqrtf(cc);
    float vn = fmaxf(sqrtf(wave_sum64(fb * fb)), 1e-10f);
    float scale = tanhf(sc * vn * 0.5f) / (sc * vn);
    b_out[(size_t)wid * DIM + lane] = fb * scale;

    float nr = fmaxf(sqrtf(wave_sum64(fs * fs)), 1e-12f);
    s_out[(size_t)wid * DIM + lane] = fs / nr;
}

extern "C" void kernel_launch(void* const* d_in, const int* in_sizes, int n_in,
                              void* d_out, int out_size, void* d_ws, size_t ws_size,
                              hipStream_t stream) {
    const float* e0   = (const float*)d_in[0];
    const float* b0   = (const float*)d_in[1];
    const float* s0   = (const float*)d_in[2];
    const float* We   = (const float*)d_in[3];
    const float* be   = (const float*)d_in[4];
    const float* Wb   = (const float*)d_in[5];
    const float* bb   = (const float*)d_in[6];
    const float* Ws   = (const float*)d_in[7];
    const float* bs   = (const float*)d_in[8];
    const float* bcurv= (const float*)d_in[9];
    const int*   src  = (const int*)d_in[11];
    const int*   dst  = (const int*)d_in[12];

    const int N = in_sizes[0] / DIM;
    const int E = in_sizes[11];
    const int L = in_sizes[3] / (DIM * DIM);

    // workspace carve — every pointer 256B-aligned (round-16 lesson: a 32B
    // misaligned hb cost +28% FETCH in phaseB: 384B rows straddle 4 granules)
    const int Npad = (N + 1023) & ~1023;
    char* wsb = (char*)d_ws;
    size_t off = 0;
    auto alloc = [&](size_t bytes) -> void* {
        off = (off + 255) & ~(size_t)255;
        void* p = wsb + off;
        off += bytes;
        return p;
    };
    int* cnt       = (int*)alloc((size_t)Npad * 4);
    int* row_start = (int*)alloc((size_t)(Npad + 64) * 4);
    int* cursor    = (int*)alloc((size_t)Npad * 4);
    int* blocksum  = (int*)alloc(1024 * 4);
    int* bcur      = (int*)alloc(1024 * 4);
    int* bcnt      = (int*)alloc(1024 * 4);
    int* bbase     = (int*)alloc(1032 * 4);
    int* csr_src   = (int*)alloc((size_t)E * 4);
    unsigned int* ebuf = (unsigned int*)alloc((size_t)E * 4);
    unsigned short* hb = (unsigned short*)alloc((size_t)(N + 1) * 192 * 2);
    unsigned short* wcvt = (unsigned short*)alloc((size_t)L * 3 * 2 * 4096 * 2);

    float* out_e = (float*)d_out;
    float* out_b = out_e + (size_t)N * DIM;
    float* out_s = out_b + (size_t)N * DIM;

    const int ntiles = (N + 15) / 16;
    const int wavesPerMode = 1024;
    const int grdA = (3 * wavesPerMode) / 4;
    const int grdE = (E + 255) / 256;
    const int grdB = (N * DIM + 255) / 256;
    const int wtot = L * 3 * 4096;
    const int grdW = (wtot + 255) / 256;
    const int NB2  = (N + 63) / 64;
    const int nchunk = (E + PCHUNK - 1) / PCHUNK;

    if (N <= 65536) {
        hipMemsetAsync(bcnt, 0, 1024 * sizeof(int), stream);
        k_wbhist<<<grdW + 1 + nchunk, 256, 0, stream>>>(
            We, Wb, Ws, wcvt, L, grdW, hb + (size_t)N * 192, dst, bcnt, E);
        k_bscan<<<1, 1024, 0, stream>>>(bcnt, bbase, bcur, row_start, N, E);
        // edge partition fused with phaseA layer 0
        k_partA0<<<nchunk + grdA, 256, 0, stream>>>(
            src, dst, bcur, ebuf, E, nchunk,
            e0, b0, s0, wcvt, be, bb, bs, hb, bcurv, N, ntiles, wavesPerMode);
        k_bfill2<<<NB2, 256, 0, stream>>>(ebuf, bbase, row_start, csr_src, N);

        k_phaseB<<<grdB, 256, 0, stream>>>(hb, row_start, csr_src,
                                           out_e, out_b, out_s, bcurv, N);
        for (int l = 1; l < L; ++l) {
            k_phaseA_mfma<<<grdA, 256, 0, stream>>>(
                out_e, out_b, out_s,
                wcvt + (size_t)l * 3 * 2 * 4096,
                be + (size_t)l * DIM, bb + (size_t)l * DIM, bs + (size_t)l * DIM,
                hb, bcurv, N, ntiles, wavesPerMode);
            k_phaseB<<<grdB, 256, 0, stream>>>(hb, row_start, csr_src,
                                               out_e, out_b, out_s, bcurv, N);
        }
    } else {
        hipMemsetAsync(cnt, 0, (size_t)N * sizeof(int), stream);
        k_wconv_fb<<<grdW + 1, 256, 0, stream>>>(We, Wb, Ws, wcvt, L, grdW,
                                                 hb + (size_t)N * 192);
        k_hist<<<grdE, 256, 0, stream>>>(dst, cnt, E);
        int nb = (N + 1023) / 1024;
        k_scan1<<<nb, 1024, 0, stream>>>(cnt, cursor, blocksum, N);
        k_scan2<<<1, 1024, 0, stream>>>(blocksum, nb);
        k_scan3<<<(N + 255) / 256, 256, 0, stream>>>(cursor, blocksum, cnt,
                                                     row_start, cursor, N);
        k_fill<<<grdE, 256, 0, stream>>>(src, dst, cursor, csr_src, E);
        for (int l = 0; l < L; ++l) {
            const float* Xe = (l == 0) ? e0 : out_e;
            const float* Xb = (l == 0) ? b0 : out_b;
            const float* Xs = (l == 0) ? s0 : out_s;
            k_phaseA_mfma<<<grdA, 256, 0, stream>>>(
                Xe, Xb, Xs,
                wcvt + (size_t)l * 3 * 2 * 4096,
                be + (size_t)l * DIM, bb + (size_t)l * DIM, bs + (size_t)l * DIM,
                hb, bcurv, N, ntiles, wavesPerMode);
            k_phaseB<<<grdB, 256, 0, stream>>>(hb, row_start, csr_src,
                                               out_e, out_b, out_s, bcurv, N);
        }
    }
}

// Round 18
// 170.356 us; speedup vs baseline: 1.1903x; 1.0029x over previous
//
#include <hip/hip_runtime.h>
#include <hip/hip_bf16.h>

#define DIM 64

typedef __attribute__((ext_vector_type(4)))  float f32x4;
typedef __attribute__((ext_vector_type(2)))  float f32x2;
typedef __attribute__((ext_vector_type(8)))  short short8;
typedef __attribute__((ext_vector_type(4)))  unsigned short u16x4;
typedef __attribute__((ext_vector_type(2)))  unsigned int u32x2;

// ---------- wave helpers (wave64) ----------
static __device__ __forceinline__ float wave_sum64(float v) {
    v += __shfl_xor(v, 1, 64);
    v += __shfl_xor(v, 2, 64);
    v += __shfl_xor(v, 4, 64);
    v += __shfl_xor(v, 8, 64);
    v += __shfl_xor(v, 16, 64);
    v += __shfl_xor(v, 32, 64);
    return v;
}

static __device__ __forceinline__ float b2f(unsigned short u) {
    return __uint_as_float(((unsigned int)u) << 16);
}
static __device__ __forceinline__ unsigned short f2b(float f) {
    unsigned int u = __float_as_uint(f);
    unsigned int rounded = u + 0x7fff + ((u >> 16) & 1);
    return (unsigned short)(rounded >> 16);
}
static __device__ __forceinline__ float b2f_lo(unsigned int u) {
    return __uint_as_float(u << 16);
}
static __device__ __forceinline__ float b2f_hi(unsigned int u) {
    return __uint_as_float(u & 0xffff0000u);
}

#define PCHUNK 8192
#define BCAP 4096

// ---------- fused wconv + zero-row + per-chunk LDS bucket histogram ----------
__global__ __launch_bounds__(256) void k_wbhist(
        const float* __restrict__ We, const float* __restrict__ Wb,
        const float* __restrict__ Ws, unsigned short* __restrict__ wcvt,
        int L, int blocksW, unsigned short* __restrict__ hb_zero_row,
        const int* __restrict__ dst, int* __restrict__ bcnt, int E) {
    __shared__ int hist[1024];
    int bid = blockIdx.x;
    if (bid < blocksW) {
        int i = bid * 256 + threadIdx.x;
        int total = L * 3 * 4096;
        if (i >= total) return;
        int pos  = i & 4095;
        int lm   = i >> 12;
        int mode = lm % 3;
        int l    = lm / 3;
        const float* W = (mode == 0) ? We : (mode == 1) ? Wb : Ws;
        float v = W[(size_t)l * 4096 + pos];
        unsigned short hi = f2b(v);
        unsigned short lo = f2b(v - b2f(hi));
        wcvt[((size_t)lm * 2 + 0) * 4096 + pos] = hi;
        wcvt[((size_t)lm * 2 + 1) * 4096 + pos] = lo;
        return;
    }
    if (bid == blocksW) {
        if (threadIdx.x < 192) hb_zero_row[threadIdx.x] = 0;
        return;
    }
    int chunk = bid - blocksW - 1;
    int base = chunk * PCHUNK;
    int cnt = E - base; if (cnt > PCHUNK) cnt = PCHUNK;
    int t = threadIdx.x;
    for (int i = t; i < 1024; i += 256) hist[i] = 0;
    __syncthreads();
    for (int k = t; k < cnt; k += 256) {
        int b = dst[base + k] >> 6;
        atomicAdd(&hist[b], 1);
    }
    __syncthreads();
    for (int b = t; b < 1024; b += 256) {
        int h = hist[b];
        if (h > 0) atomicAdd(&bcnt[b], h);
    }
}

// single block: scan bucket counts -> bbase (exclusive), init bcur, row_start[n]=E
__global__ __launch_bounds__(1024) void k_bscan(const int* __restrict__ bcnt,
                                                int* __restrict__ bbase,
                                                int* __restrict__ bcur,
                                                int* __restrict__ row_start,
                                                int n, int E) {
    __shared__ int buf[1024];
    int t = threadIdx.x;
    int v = bcnt[t];
    buf[t] = v;
    __syncthreads();
    for (int off = 1; off < 1024; off <<= 1) {
        int x = (t >= off) ? buf[t - off] : 0;
        __syncthreads();
        buf[t] += x;
        __syncthreads();
    }
    int excl = buf[t] - v;
    bbase[t] = excl;
    bcur[t]  = excl;
    if (t == 1023) {
        bbase[1024] = buf[1023];
        row_start[n] = E;
    }
}

// ---------- Phase A body (XBF16: input rows are bf16 [node][mode*64+f]) ----------
// hb column order within a mode is PERMUTED: packed col c = 4*mrow + t holds
// feature f = 16*t + mrow. Aggregation commutes; phaseB un-permutes.
template <bool XBF16>
static __device__ __forceinline__ void phaseA_body(
        int gw, int lane,
        const float* __restrict__ Xe, const float* __restrict__ Xb, const float* __restrict__ Xs,
        const unsigned short* __restrict__ Xb16,
        const unsigned short* __restrict__ wcvt,
        const float* __restrict__ be, const float* __restrict__ bb, const float* __restrict__ bs,
        unsigned short* __restrict__ hb, const float* __restrict__ curv,
        int n, int ntiles, int wavesPerMode) {
    int mode = gw / wavesPerMode;
    if (mode >= 3) return;
    int w0   = gw - mode * wavesPerMode;

    int mrow  = lane & 15;
    int half  = lane >> 4;

    const float* X    = (mode == 0) ? Xe : (mode == 1) ? Xb : Xs;
    const float* bias = (mode == 0) ? be : (mode == 1) ? bb : bs;
    float sc = sqrtf(curv[0]);

    const unsigned short* whi = wcvt + ((size_t)mode * 2 + 0) * 4096;
    const unsigned short* wlo = wcvt + ((size_t)mode * 2 + 1) * 4096;
    short8 b_hi[4][2], b_lo[4][2];
#pragma unroll
    for (int t = 0; t < 4; ++t) {
        int wrow = 16 * t + mrow;
#pragma unroll
        for (int kc = 0; kc < 2; ++kc) {
            int off = wrow * DIM + 32 * kc + 8 * half;
            b_hi[t][kc] = *reinterpret_cast<const short8*>(whi + off);
            b_lo[t][kc] = *reinterpret_cast<const short8*>(wlo + off);
        }
    }
    float bl[4];
#pragma unroll
    for (int t = 0; t < 4; ++t) bl[t] = bias[16 * t + mrow];

    for (int tile = w0; tile < ntiles; tile += wavesPerMode) {
        int node0 = tile * 16;
        int row = node0 + mrow;
        int rowc = (row < n) ? row : (n - 1);
        float xv[16];
        if constexpr (XBF16) {
            const unsigned short* xp = Xb16 + (size_t)rowc * 192 + mode * 64 + 8 * half;
            short8 v0 = *reinterpret_cast<const short8*>(xp);
            short8 v1 = *reinterpret_cast<const short8*>(xp + 32);
#pragma unroll
            for (int i = 0; i < 8; ++i) {
                xv[i]     = b2f((unsigned short)v0[i]);
                xv[8 + i] = b2f((unsigned short)v1[i]);
            }
        } else {
            const float* xp = X + (size_t)rowc * DIM + 8 * half;
            const float4* p0 = reinterpret_cast<const float4*>(xp);
            const float4* p1 = reinterpret_cast<const float4*>(xp + 32);
            float4 a = p0[0], b = p0[1], c = p1[0], d = p1[1];
            xv[0]=a.x; xv[1]=a.y; xv[2]=a.z; xv[3]=a.w;
            xv[4]=b.x; xv[5]=b.y; xv[6]=b.z; xv[7]=b.w;
            xv[8]=c.x; xv[9]=c.y; xv[10]=c.z; xv[11]=c.w;
            xv[12]=d.x; xv[13]=d.y; xv[14]=d.z; xv[15]=d.w;
        }

        float scale = 1.0f;
        if (mode != 0) {
            float ss = 0.f;
#pragma unroll
            for (int i = 0; i < 16; ++i) ss = fmaf(xv[i], xv[i], ss);
            ss += __shfl_xor(ss, 16, 64);
            ss += __shfl_xor(ss, 32, 64);
            if (mode == 1) {
                float dn = fmaxf(sqrtf(ss), 1e-10f);
                scale = (2.0f / sc) * atanhf(sc * dn) / dn;
            } else {
                float dn = fmaxf(sqrtf(ss), 1e-12f);
                scale = 1.0f / dn;
            }
        }

        short8 a_hi0, a_hi1, a_lo0, a_lo1;
#pragma unroll
        for (int i = 0; i < 8; ++i) {
            float s0 = xv[i] * scale;
            unsigned short h0 = f2b(s0);
            a_hi0[i] = (short)h0;
            a_lo0[i] = (short)f2b(s0 - b2f(h0));
            float s1 = xv[8 + i] * scale;
            unsigned short h1 = f2b(s1);
            a_hi1[i] = (short)h1;
            a_lo1[i] = (short)f2b(s1 - b2f(h1));
        }

        f32x4 acc[4];
#pragma unroll
        for (int t = 0; t < 4; ++t) {
            f32x4 a = {0.f, 0.f, 0.f, 0.f};
            a = __builtin_amdgcn_mfma_f32_16x16x32_bf16(a_hi0, b_hi[t][0], a, 0, 0, 0);
            a = __builtin_amdgcn_mfma_f32_16x16x32_bf16(a_hi1, b_hi[t][1], a, 0, 0, 0);
            a = __builtin_amdgcn_mfma_f32_16x16x32_bf16(a_lo0, b_hi[t][0], a, 0, 0, 0);
            a = __builtin_amdgcn_mfma_f32_16x16x32_bf16(a_lo1, b_hi[t][1], a, 0, 0, 0);
            a = __builtin_amdgcn_mfma_f32_16x16x32_bf16(a_hi0, b_lo[t][0], a, 0, 0, 0);
            a = __builtin_amdgcn_mfma_f32_16x16x32_bf16(a_hi1, b_lo[t][1], a, 0, 0, 0);
            acc[t] = a;
        }

        float v[4][4];
#pragma unroll
        for (int t = 0; t < 4; ++t) {
#pragma unroll
            for (int r = 0; r < 4; ++r) v[t][r] = acc[t][r] + bl[t];
        }

        if (mode == 2) {
#pragma unroll
            for (int r = 0; r < 4; ++r) {
                float s = v[0][r]*v[0][r] + v[1][r]*v[1][r] + v[2][r]*v[2][r] + v[3][r]*v[3][r];
                s += __shfl_xor(s, 1, 64);
                s += __shfl_xor(s, 2, 64);
                s += __shfl_xor(s, 4, 64);
                s += __shfl_xor(s, 8, 64);
                float inv = 1.0f / fmaxf(sqrtf(s), 1e-12f);
#pragma unroll
                for (int t = 0; t < 4; ++t) v[t][r] *= inv;
            }
        }

#pragma unroll
        for (int r = 0; r < 4; ++r) {
            int orow = node0 + half * 4 + r;
            if (orow < n) {
                u16x4 pk;
                pk.x = f2b(v[0][r]); pk.y = f2b(v[1][r]);
                pk.z = f2b(v[2][r]); pk.w = f2b(v[3][r]);
                *reinterpret_cast<u16x4*>(hb + (size_t)orow * 192 + mode * 64 + 4 * mrow) = pk;
            }
        }
    }
}

// standalone phase A
template <bool XBF16>
__global__ __launch_bounds__(256) void k_phaseA_mfma(
        const float* __restrict__ Xe, const float* __restrict__ Xb, const float* __restrict__ Xs,
        const unsigned short* __restrict__ Xb16,
        const unsigned short* __restrict__ wcvt,
        const float* __restrict__ be, const float* __restrict__ bb, const float* __restrict__ bs,
        unsigned short* __restrict__ hb, const float* __restrict__ curv,
        int n, int ntiles, int wavesPerMode) {
    int gtid = blockIdx.x * blockDim.x + threadIdx.x;
    phaseA_body<XBF16>(gtid >> 6, gtid & 63, Xe, Xb, Xs, Xb16, wcvt, be, bb, bs,
                       hb, curv, n, ntiles, wavesPerMode);
}

// ---------- fused: edge partition (pass 1) + phase A layer 0 (f32 inputs) ----------
__global__ __launch_bounds__(256) void k_partA0(
        const int* __restrict__ src, const int* __restrict__ dst,
        int* __restrict__ bcur, unsigned int* __restrict__ ebuf, int E, int blocksP,
        const float* __restrict__ Xe, const float* __restrict__ Xb, const float* __restrict__ Xs,
        const unsigned short* __restrict__ wcvt,
        const float* __restrict__ be, const float* __restrict__ bb, const float* __restrict__ bs,
        unsigned short* __restrict__ hb, const float* __restrict__ curv,
        int n, int ntiles, int wavesPerMode) {
    if ((int)blockIdx.x >= blocksP) {
        int gtid = (blockIdx.x - blocksP) * 256 + threadIdx.x;
        phaseA_body<false>(gtid >> 6, gtid & 63, Xe, Xb, Xs, nullptr, wcvt,
                           be, bb, bs, hb, curv, n, ntiles, wavesPerMode);
        return;
    }
    __shared__ int hist[1024];
    __shared__ int aux[256];
    __shared__ int delta[1024];
    __shared__ unsigned int stage[PCHUNK];

    int t = threadIdx.x;
    int base = blockIdx.x * PCHUNK;
    int cnt = E - base; if (cnt > PCHUNK) cnt = PCHUNK;

#pragma unroll
    for (int i = t; i < 1024; i += 256) hist[i] = 0;
    __syncthreads();

    for (int k = t; k < cnt; k += 256) {
        int b = dst[base + k] >> 6;
        atomicAdd(&hist[b], 1);
    }
    __syncthreads();

    int i4 = 4 * t;
    int a0 = hist[i4], a1 = hist[i4 + 1], a2 = hist[i4 + 2], a3 = hist[i4 + 3];
    int s = a0 + a1 + a2 + a3;
    aux[t] = s;
    __syncthreads();
    for (int off = 1; off < 256; off <<= 1) {
        int x = (t >= off) ? aux[t - off] : 0;
        __syncthreads();
        aux[t] += x;
        __syncthreads();
    }
    int excl = aux[t] - s;
    hist[i4]     = excl;
    hist[i4 + 1] = excl + a0;
    hist[i4 + 2] = excl + a0 + a1;
    hist[i4 + 3] = excl + a0 + a1 + a2;
    __syncthreads();

    int total = aux[255];
    for (int b = t; b < 1024; b += 256) {
        int st = hist[b];
        int nx = (b + 1 < 1024) ? hist[b + 1] : total;
        int cb = nx - st;
        if (cb > 0) {
            int gb = atomicAdd(&bcur[b], cb);
            delta[b] = gb - st;
        }
    }
    __syncthreads();

    for (int k = t; k < cnt; k += 256) {
        unsigned int d = (unsigned int)dst[base + k];
        unsigned int sv = (unsigned int)src[base + k];
        int b = (int)(d >> 6);
        int pos = atomicAdd(&hist[b], 1);
        stage[pos] = (d << 16) | sv;
    }
    __syncthreads();

    for (int p = t; p < cnt; p += 256) {
        unsigned int v = stage[p];
        int b = (int)(v >> 22);
        ebuf[delta[b] + p] = v;
    }
}

// Pass 2: per-bucket: per-node counts in LDS -> row_start (coalesced) + CSR slice.
__global__ __launch_bounds__(256) void k_bfill2(const unsigned int* __restrict__ ebuf,
                                                const int* __restrict__ bbase,
                                                int* __restrict__ row_start,
                                                int* __restrict__ csr_src,
                                                int n) {
    __shared__ int cnt64[64];
    __shared__ int lcur[64];
    __shared__ unsigned int evals[BCAP];
    __shared__ int lcsr[BCAP];
    int b = blockIdx.x;
    int t = threadIdx.x;
    int nodeLo = b * 64;
    int gLo = bbase[b];
    int gHi = bbase[b + 1];
    int cntB = gHi - gLo;

    if (t < 64) cnt64[t] = 0;
    __syncthreads();

    if (cntB <= BCAP) {
        for (int p = t; p < cntB; p += 256) {
            unsigned int v = ebuf[gLo + p];
            evals[p] = v;
            atomicAdd(&cnt64[(int)(v >> 16) - nodeLo], 1);
        }
        __syncthreads();
        int v0 = (t < 64) ? cnt64[t] : 0;
        for (int off = 1; off < 64; off <<= 1) {
            int x = (t < 64 && t >= off) ? cnt64[t - off] : 0;
            __syncthreads();
            if (t < 64) cnt64[t] += x;
            __syncthreads();
        }
        if (t < 64) {
            int pref = cnt64[t] - v0;
            lcur[t] = pref;
            int node = nodeLo + t;
            if (node < n) row_start[node] = gLo + pref;
        }
        __syncthreads();
        for (int p = t; p < cntB; p += 256) {
            unsigned int v = evals[p];
            int li = (int)(v >> 16) - nodeLo;
            int slot = atomicAdd(&lcur[li], 1);
            lcsr[slot] = (int)(v & 0xFFFFu);
        }
        __syncthreads();
        for (int p = t; p < cntB; p += 256) csr_src[gLo + p] = lcsr[p];
    } else {
        for (int p = t; p < cntB; p += 256) {
            unsigned int v = ebuf[gLo + p];
            atomicAdd(&cnt64[(int)(v >> 16) - nodeLo], 1);
        }
        __syncthreads();
        int v0 = (t < 64) ? cnt64[t] : 0;
        for (int off = 1; off < 64; off <<= 1) {
            int x = (t < 64 && t >= off) ? cnt64[t - off] : 0;
            __syncthreads();
            if (t < 64) cnt64[t] += x;
            __syncthreads();
        }
        if (t < 64) {
            int pref = cnt64[t] - v0;
            lcur[t] = pref;
            int node = nodeLo + t;
            if (node < n) row_start[node] = gLo + pref;
        }
        __syncthreads();
        for (int p = t; p < cntB; p += 256) {
            unsigned int v = ebuf[gLo + p];
            int li = (int)(v >> 16) - nodeLo;
            int slot = atomicAdd(&lcur[li], 1);
            csr_src[gLo + slot] = (int)(v & 0xFFFFu);
        }
    }
}

// ---------- fallback CSR path (N > 65536 only) ----------
__global__ void k_hist(const int* __restrict__ dst, int* __restrict__ cnt, int E) {
    int e = blockIdx.x * blockDim.x + threadIdx.x;
    if (e < E) atomicAdd(&cnt[dst[e]], 1);
}
__global__ __launch_bounds__(1024) void k_scan1(const int* __restrict__ cnt,
                                                int* __restrict__ partial,
                                                int* __restrict__ blocksum, int n) {
    __shared__ int buf[1024];
    int t = threadIdx.x;
    int i = blockIdx.x * 1024 + t;
    int v = (i < n) ? cnt[i] : 0;
    buf[t] = v;
    __syncthreads();
    for (int off = 1; off < 1024; off <<= 1) {
        int x = (t >= off) ? buf[t - off] : 0;
        __syncthreads();
        buf[t] += x;
        __syncthreads();
    }
    if (i < n) partial[i] = buf[t];
    if (t == 1023) blocksum[blockIdx.x] = buf[1023];
}
__global__ __launch_bounds__(1024) void k_scan2(int* __restrict__ blocksum, int nb) {
    __shared__ int buf[1024];
    int t = threadIdx.x;
    buf[t] = (t < nb) ? blocksum[t] : 0;
    __syncthreads();
    for (int off = 1; off < 1024; off <<= 1) {
        int x = (t >= off) ? buf[t - off] : 0;
        __syncthreads();
        buf[t] += x;
        __syncthreads();
    }
    if (t < nb) blocksum[t] = buf[t];
}
__global__ void k_scan3(const int* __restrict__ partial, const int* __restrict__ blocksum,
                        const int* __restrict__ cnt,
                        int* __restrict__ row_start, int* __restrict__ cursor, int n) {
    int i = blockIdx.x * blockDim.x + threadIdx.x;
    if (i == 0) row_start[0] = 0;
    if (i < n) {
        int b = i >> 10;
        int add = (b > 0) ? blocksum[b - 1] : 0;
        int incl = partial[i] + add;
        row_start[i + 1] = incl;
        cursor[i] = incl - cnt[i];
    }
}
__global__ void k_fill(const int* __restrict__ src, const int* __restrict__ dst,
                       int* __restrict__ cursor, int* __restrict__ csr_src, int E) {
    int e = blockIdx.x * blockDim.x + threadIdx.x;
    if (e < E) {
        int p = atomicAdd(&cursor[dst[e]], 1);
        csr_src[p] = src[e];
    }
}
__global__ __launch_bounds__(256) void k_wconv_fb(
        const float* __restrict__ We, const float* __restrict__ Wb,
        const float* __restrict__ Ws, unsigned short* __restrict__ wcvt,
        int L, int blocksW, unsigned short* __restrict__ hb_zero_row) {
    if ((int)blockIdx.x >= blocksW) {
        if (threadIdx.x < 192) hb_zero_row[threadIdx.x] = 0;
        return;
    }
    int i = blockIdx.x * 256 + threadIdx.x;
    int total = L * 3 * 4096;
    if (i >= total) return;
    int pos  = i & 4095;
    int lm   = i >> 12;
    int mode = lm % 3;
    int l    = lm / 3;
    const float* W = (mode == 0) ? We : (mode == 1) ? Wb : Ws;
    float v = W[(size_t)l * 4096 + pos];
    unsigned short hi = f2b(v);
    unsigned short lo = f2b(v - b2f(hi));
    wcvt[((size_t)lm * 2 + 0) * 4096 + pos] = hi;
    wcvt[((size_t)lm * 2 + 1) * 4096 + pos] = lo;
}

// ---------- Phase B: asm gathers + zero-row tails + packed f32 adds ----------
// OUT_BF16: write aggregated rows as bf16 [node][mode*64+f] (intermediate layer
// staging — layer-0 outputs are consumed only by phaseA layer 1).
#define GL(i, gname, vt) \
    "v_readlane_b32 %[st], %[idx], " #i "\n\t" \
    "s_mul_i32 %[st], %[st], 384\n\t" \
    "v_add_u32 %[" vt "], %[st], %[lo]\n\t" \
    "global_load_dwordx2 %[" gname "], %[" vt "], %[bs]\n\t"

#define ACC2(gi) { \
    f32x2 v01, v23; \
    v01.x = b2f_lo(gi.x); v01.y = b2f_hi(gi.x); \
    v23.x = b2f_lo(gi.y); v23.y = b2f_hi(gi.y); \
    asm volatile("v_pk_add_f32 %0, %1, %0" : "+v"(a01) : "v"(v01)); \
    asm volatile("v_pk_add_f32 %0, %1, %0" : "+v"(a23) : "v"(v23)); }

template <bool OUT_BF16>
__global__ __launch_bounds__(256) void k_phaseB(const unsigned short* __restrict__ hb,
                                                const int* __restrict__ row_start,
                                                const int* __restrict__ csr_src,
                                                float* __restrict__ e_out,
                                                float* __restrict__ b_out,
                                                float* __restrict__ s_out,
                                                unsigned short* __restrict__ xout,
                                                const float* __restrict__ curv,
                                                int n) {
    __shared__ float smem[4][192];
    int gtid = blockIdx.x * blockDim.x + threadIdx.x;
    int wid  = gtid >> 6;
    int lane = threadIdx.x & 63;
    int w    = threadIdx.x >> 6;
    if (wid >= n) return;

    int beg = row_start[wid];
    int end = row_start[wid + 1];

    const void* hbp = (const void*)hb;
    unsigned int lane_off = (unsigned int)lane * 8u;
    bool active = lane < 48;

    f32x2 a01 = {0.f, 0.f};
    f32x2 a23 = {0.f, 0.f};

    if (active) {
        int li0 = beg + (lane & 15);
        int lic0 = (li0 < end) ? li0 : (end - 1);
        unsigned int tv0 = (end > beg) ? (unsigned int)csr_src[lic0] : (unsigned int)n;
        unsigned int idxv = (li0 < end) ? tv0 : (unsigned int)n;

        for (int j = beg; j < end; j += 16) {
            u32x2 g0, g1, g2, g3, g4, g5, g6, g7;
            u32x2 g8, g9, g10, g11, g12, g13, g14, g15;
            unsigned int st, vt0, vt1;
            asm volatile(
                GL(0,  "g0",  "vt0") GL(1,  "g1",  "vt1")
                GL(2,  "g2",  "vt0") GL(3,  "g3",  "vt1")
                GL(4,  "g4",  "vt0") GL(5,  "g5",  "vt1")
                GL(6,  "g6",  "vt0") GL(7,  "g7",  "vt1")
                GL(8,  "g8",  "vt0") GL(9,  "g9",  "vt1")
                GL(10, "g10", "vt0") GL(11, "g11", "vt1")
                GL(12, "g12", "vt0") GL(13, "g13", "vt1")
                GL(14, "g14", "vt0") GL(15, "g15", "vt1")
                : [g0]"=&v"(g0),  [g1]"=&v"(g1),  [g2]"=&v"(g2),  [g3]"=&v"(g3),
                  [g4]"=&v"(g4),  [g5]"=&v"(g5),  [g6]"=&v"(g6),  [g7]"=&v"(g7),
                  [g8]"=&v"(g8),  [g9]"=&v"(g9),  [g10]"=&v"(g10),[g11]"=&v"(g11),
                  [g12]"=&v"(g12),[g13]"=&v"(g13),[g14]"=&v"(g14),[g15]"=&v"(g15),
                  [st]"=&s"(st), [vt0]"=&v"(vt0), [vt1]"=&v"(vt1)
                : [idx]"v"(idxv), [lo]"v"(lane_off), [bs]"s"(hbp)
                : "memory");

            int jn = j + 16;
            unsigned int idx_next = idxv;
            if (jn < end) {
                int li = jn + (lane & 15);
                int lic = (li < end) ? li : (end - 1);
                unsigned int tv = (unsigned int)csr_src[lic];
                idx_next = (li < end) ? tv : (unsigned int)n;
            }

            asm volatile("s_waitcnt vmcnt(0)" ::: "memory");
            __builtin_amdgcn_sched_barrier(0);

            ACC2(g0)  ACC2(g1)  ACC2(g2)  ACC2(g3)
            ACC2(g4)  ACC2(g5)  ACC2(g6)  ACC2(g7)
            ACC2(g8)  ACC2(g9)  ACC2(g10) ACC2(g11)
            ACC2(g12) ACC2(g13) ACC2(g14) ACC2(g15)

            idxv = idx_next;
        }
        smem[w][4 * lane + 0] = a01.x;
        smem[w][4 * lane + 1] = a01.y;
        smem[w][4 * lane + 2] = a23.x;
        smem[w][4 * lane + 3] = a23.y;
    }
    asm volatile("s_waitcnt lgkmcnt(0)" ::: "memory");

    int c = 4 * (lane & 15) + (lane >> 4);
    float fe = smem[w][c];
    float fb = smem[w][64 + c];
    float fs = smem[w][128 + c];

    int cnt = end - beg;
    float inv = 1.0f / (float)(cnt > 0 ? cnt : 1);
    fe *= inv; fb *= inv; fs *= inv;

    float ve = (fe >= 0.f) ? fe : 0.2f * fe;

    float cc = curv[0];
    float sc = sqrtf(cc);
    float vn = fmaxf(sqrtf(wave_sum64(fb * fb)), 1e-10f);
    float scale = tanhf(sc * vn * 0.5f) / (sc * vn);
    float vb = fb * scale;

    float nr = fmaxf(sqrtf(wave_sum64(fs * fs)), 1e-12f);
    float vs = fs / nr;

    if constexpr (OUT_BF16) {
        unsigned short* xr = xout + (size_t)wid * 192;
        xr[lane]       = f2b(ve);
        xr[64 + lane]  = f2b(vb);
        xr[128 + lane] = f2b(vs);
    } else {
        e_out[(size_t)wid * DIM + lane] = ve;
        b_out[(size_t)wid * DIM + lane] = vb;
        s_out[(size_t)wid * DIM + lane] = vs;
    }
}

extern "C" void kernel_launch(void* const* d_in, const int* in_sizes, int n_in,
                              void* d_out, int out_size, void* d_ws, size_t ws_size,
                              hipStream_t stream) {
    const float* e0   = (const float*)d_in[0];
    const float* b0   = (const float*)d_in[1];
    const float* s0   = (const float*)d_in[2];
    const float* We   = (const float*)d_in[3];
    const float* be   = (const float*)d_in[4];
    const float* Wb   = (const float*)d_in[5];
    const float* bb   = (const float*)d_in[6];
    const float* Ws   = (const float*)d_in[7];
    const float* bs   = (const float*)d_in[8];
    const float* bcurv= (const float*)d_in[9];
    const int*   src  = (const int*)d_in[11];
    const int*   dst  = (const int*)d_in[12];

    const int N = in_sizes[0] / DIM;
    const int E = in_sizes[11];
    const int L = in_sizes[3] / (DIM * DIM);

    // workspace carve — every pointer 256B-aligned (round-16 lesson)
    const int Npad = (N + 1023) & ~1023;
    char* wsb = (char*)d_ws;
    size_t off = 0;
    auto alloc = [&](size_t bytes) -> void* {
        off = (off + 255) & ~(size_t)255;
        void* p = wsb + off;
        off += bytes;
        return p;
    };
    int* cnt       = (int*)alloc((size_t)Npad * 4);
    int* row_start = (int*)alloc((size_t)(Npad + 64) * 4);
    int* cursor    = (int*)alloc((size_t)Npad * 4);
    int* blocksum  = (int*)alloc(1024 * 4);
    int* bcur      = (int*)alloc(1024 * 4);
    int* bcnt      = (int*)alloc(1024 * 4);
    int* bbase     = (int*)alloc(1032 * 4);
    int* csr_src   = (int*)alloc((size_t)E * 4);
    unsigned int* ebuf = (unsigned int*)alloc((size_t)E * 4);
    unsigned short* hb = (unsigned short*)alloc((size_t)(N + 1) * 192 * 2);
    unsigned short* wcvt = (unsigned short*)alloc((size_t)L * 3 * 2 * 4096 * 2);
    unsigned short* xstage = (unsigned short*)alloc((size_t)N * 192 * 2);

    float* out_e = (float*)d_out;
    float* out_b = out_e + (size_t)N * DIM;
    float* out_s = out_b + (size_t)N * DIM;

    const int ntiles = (N + 15) / 16;
    const int wavesPerMode = 1024;
    const int grdA = (3 * wavesPerMode) / 4;
    const int grdE = (E + 255) / 256;
    const int grdB = (N * DIM + 255) / 256;
    const int wtot = L * 3 * 4096;
    const int grdW = (wtot + 255) / 256;
    const int NB2  = (N + 63) / 64;
    const int nchunk = (E + PCHUNK - 1) / PCHUNK;

    if (N <= 65536) {
        hipMemsetAsync(bcnt, 0, 1024 * sizeof(int), stream);
        k_wbhist<<<grdW + 1 + nchunk, 256, 0, stream>>>(
            We, Wb, Ws, wcvt, L, grdW, hb + (size_t)N * 192, dst, bcnt, E);
        k_bscan<<<1, 1024, 0, stream>>>(bcnt, bbase, bcur, row_start, N, E);
        k_partA0<<<nchunk + grdA, 256, 0, stream>>>(
            src, dst, bcur, ebuf, E, nchunk,
            e0, b0, s0, wcvt, be, bb, bs, hb, bcurv, N, ntiles, wavesPerMode);
        k_bfill2<<<NB2, 256, 0, stream>>>(ebuf, bbase, row_start, csr_src, N);

        for (int l = 0; l < L; ++l) {
            if (l > 0) {
                k_phaseA_mfma<true><<<grdA, 256, 0, stream>>>(
                    nullptr, nullptr, nullptr, xstage,
                    wcvt + (size_t)l * 3 * 2 * 4096,
                    be + (size_t)l * DIM, bb + (size_t)l * DIM, bs + (size_t)l * DIM,
                    hb, bcurv, N, ntiles, wavesPerMode);
            }
            if (l == L - 1) {
                k_phaseB<false><<<grdB, 256, 0, stream>>>(
                    hb, row_start, csr_src, out_e, out_b, out_s, nullptr, bcurv, N);
            } else {
                k_phaseB<true><<<grdB, 256, 0, stream>>>(
                    hb, row_start, csr_src, nullptr, nullptr, nullptr, xstage, bcurv, N);
            }
        }
    } else {
        hipMemsetAsync(cnt, 0, (size_t)N * sizeof(int), stream);
        k_wconv_fb<<<grdW + 1, 256, 0, stream>>>(We, Wb, Ws, wcvt, L, grdW,
                                                 hb + (size_t)N * 192);
        k_hist<<<grdE, 256, 0, stream>>>(dst, cnt, E);
        int nb = (N + 1023) / 1024;
        k_scan1<<<nb, 1024, 0, stream>>>(cnt, cursor, blocksum, N);
        k_scan2<<<1, 1024, 0, stream>>>(blocksum, nb);
        k_scan3<<<(N + 255) / 256, 256, 0, stream>>>(cursor, blocksum, cnt,
                                                     row_start, cursor, N);
        k_fill<<<grdE, 256, 0, stream>>>(src, dst, cursor, csr_src, E);
        for (int l = 0; l < L; ++l) {
            const float* Xe = (l == 0) ? e0 : out_e;
            const float* Xb = (l == 0) ? b0 : out_b;
            const float* Xs = (l == 0) ? s0 : out_s;
            k_phaseA_mfma<false><<<grdA, 256, 0, stream>>>(
                Xe, Xb, Xs, nullptr,
                wcvt + (size_t)l * 3 * 2 * 4096,
                be + (size_t)l * DIM, bb + (size_t)l * DIM, bs + (size_t)l * DIM,
                hb, bcurv, N, ntiles, wavesPerMode);
            k_phaseB<false><<<grdB, 256, 0, stream>>>(
                hb, row_start, csr_src, out_e, out_b, out_s, nullptr, bcurv, N);
        }
    }
}